// Round 21
// baseline (929.995 us; speedup 1.0000x reference)
//
#include <hip/hip_runtime.h>

// DMMRLoss_52621939310662 — round 21: r16 champion + row-wise conv2 (b128) only.
// Model: r16 is LDS-instruction-bound (~31k LDS-pipe cyc/wave ≈ 440us measured).
// Change: conv2 reads 4536 scalar broadcast b32 -> 784 ds_read_b128 (49 rows x
// 2 per icl-half, each row reused by all legal (td,th) taps; zrow/yrow fully
// unrolled so acc2 indices stay compile-time). Weights w[27] hoisted per icl.
// conv1/staging/fc1 byte-identical to r16. Bounds (256,2): kill spill risk
// (r19/r20: acc-heavy structures spill at (256,3/4); r14: (256,2)->92 VGPR ok).
// Spill canary: WRITE_SIZE must be ~140 B.

static constexpr int kPS = 433;    // staging plane stride (4-way floor)
static constexpr int kRS = 25;     // staging row stride
static constexpr int kCS = 552;    // conv1-out channel stride (mult 4 -> 16B rows)
static constexpr int kZS = 68;     // conv1-out z stride (mult 4)
static constexpr int kHOff = 6912; // h[k] region after partials

template <bool WPACK>
static __device__ __forceinline__ float2 dmr21_patch(
    int p, int t,
    const float* __restrict__ src, const float* __restrict__ tgt,
    const float* __restrict__ c1w, const float* __restrict__ c1b,
    const float* __restrict__ c2w, const float* __restrict__ c2b,
    const float* __restrict__ fw1, const float* __restrict__ f1b,
    const float* __restrict__ f2w, const float* __restrict__ f2b,
    float* __restrict__ sBuf, float* __restrict__ sRed) {
  int pd = p / 169; int rem = p - pd * 169; int phh = rem / 13; int pww = rem - phh * 13;
  int z0 = pd * 17, y0 = phh * 17, x0 = pww * 17;

  int wv  = t >> 6;                   // wave 0..3
  int od  = (t >> 3) & 7, oh = t & 7;
  int oc2 = t & 63;

  // ---- stage tgt patch (padded layout) + count zeros ----
  float cnt = 0.f;
  for (int idx = t; idx < 4913; idx += 256) {
    int a = idx / 289; int r2 = idx - a * 289; int b = r2 / 17; int c = r2 - b * 17;
    float v = tgt[((size_t)(z0 + a) * 222 + (y0 + b)) * 222 + (x0 + c)];
    sBuf[a * kPS + b * kRS + c] = v;
    if (v == 0.0f) cnt += 1.f;
  }
  sRed[t] = cnt;
  __syncthreads();
  for (int o = 128; o > 0; o >>= 1) {
    if (t < o) sRed[t] += sRed[t + o];
    __syncthreads();
  }
  float keep = (sRed[0] / 4913.0f <= 0.5f) ? 1.0f : 0.0f;
  __syncthreads();

  float acc2[27];
  #pragma unroll
  for (int i = 0; i < 27; i++) acc2[i] = 0.f;

  #pragma unroll 1
  for (int half = 0; half < 2; half++) {
    // ---- conv1 (r16 form): acc[4][8], restage per (half,ic) ----
    float acc[4][8];
    #pragma unroll
    for (int i = 0; i < 4; i++)
      #pragma unroll
      for (int j = 0; j < 8; j++) acc[i][j] = 0.f;

    #pragma unroll 1
    for (int ic = 0; ic < 2; ic++) {
      if (half + ic > 0) {            // restage: src (ic1) or tgt (half1/ic0)
        const float* vol = ic ? src : tgt;
        __syncthreads();
        for (int idx = t; idx < 4913; idx += 256) {
          int a = idx / 289; int r2 = idx - a * 289; int b = r2 / 17; int c = r2 - b * 17;
          sBuf[a * kPS + b * kRS + c] =
              vol[((size_t)(z0 + a) * 222 + (y0 + b)) * 222 + (x0 + c)];
        }
        __syncthreads();
      }
      #pragma unroll 1
      for (int td = 0; td < 3; td++) {
        #pragma unroll 1
        for (int th = 0; th < 3; th++) {
          int rbase = (2 * od + td) * kPS + (2 * oh + th) * kRS;
          float a[17];
          #pragma unroll
          for (int x = 0; x < 17; x++) a[x] = sBuf[rbase + x];
          #pragma unroll
          for (int ocr = 0; ocr < 4; ocr++) {
            int oc = half * 16 + wv * 4 + ocr;
            const float* wp = c1w + oc * 54 + ic * 27 + td * 9 + th * 3;
            float w0 = wp[0], w1 = wp[1], w2 = wp[2];
            #pragma unroll
            for (int ow = 0; ow < 8; ow++)
              acc[ocr][ow] += a[2 * ow] * w0 + a[2 * ow + 1] * w1 + a[2 * ow + 2] * w2;
          }
        }
      }
    }
    __syncthreads();                  // conv1 reads of staged patch done
    #pragma unroll
    for (int ocr = 0; ocr < 4; ocr++) {
      int lo = wv * 4 + ocr;
      float b = c1b[half * 16 + lo];
      int base = lo * kCS + od * kZS + oh * 8;      // 16B-aligned
      float4 v0, v1;
      v0.x = fmaxf(acc[ocr][0] + b, 0.f); v0.y = fmaxf(acc[ocr][1] + b, 0.f);
      v0.z = fmaxf(acc[ocr][2] + b, 0.f); v0.w = fmaxf(acc[ocr][3] + b, 0.f);
      v1.x = fmaxf(acc[ocr][4] + b, 0.f); v1.y = fmaxf(acc[ocr][5] + b, 0.f);
      v1.z = fmaxf(acc[ocr][6] + b, 0.f); v1.w = fmaxf(acc[ocr][7] + b, 0.f);
      *(float4*)&sBuf[base]     = v0;
      *(float4*)&sBuf[base + 4] = v1;
    }
    __syncthreads();

    // ---- conv2, row-restructured: per icl, 27 weights in regs; 49 rows
    //      loaded once each as 2x b128; all legal (td,th) taps applied.
    #pragma unroll 1
    for (int icr = 0; icr < 4; icr++) {
      int icl = wv * 4 + icr;
      int ic  = half * 16 + icl;
      const float* cbase = sBuf + icl * kCS;
      float w[27];
      {
        const float* wp = c2w + (size_t)oc2 * 864 + ic * 27;
        #pragma unroll
        for (int j = 0; j < 27; j++) w[j] = wp[j];
      }
      #pragma unroll
      for (int zrow = 0; zrow < 7; zrow++) {
        #pragma unroll
        for (int yrow = 0; yrow < 7; yrow++) {
          const float4* rp4 = (const float4*)(cbase + zrow * kZS + yrow * 8);
          float4 r0 = rp4[0], r1 = rp4[1];           // broadcast b128
          float row[8] = {r0.x, r0.y, r0.z, r0.w, r1.x, r1.y, r1.z, r1.w};
          #pragma unroll
          for (int td = 0; td < 3; td++) {
            int zo2 = zrow - td;
            if (zo2 < 0 || zo2 > 4 || (zo2 & 1)) continue;   // folds at compile time
            int zo = zo2 >> 1;
            #pragma unroll
            for (int th = 0; th < 3; th++) {
              int yo2 = yrow - th;
              if (yo2 < 0 || yo2 > 4 || (yo2 & 1)) continue;
              int yo = yo2 >> 1;
              float w0 = w[td * 9 + th * 3 + 0];
              float w1 = w[td * 9 + th * 3 + 1];
              float w2 = w[td * 9 + th * 3 + 2];
              #pragma unroll
              for (int xo = 0; xo < 3; xo++)
                acc2[zo * 9 + yo * 3 + xo] +=
                    row[2 * xo] * w0 + row[2 * xo + 1] * w1 + row[2 * xo + 2] * w2;
            }
          }
        }
      }
    }
  }
  __syncthreads();
  // cross-wave reduce of conv2 partials: [wv][pos][oc] in [0, 6912)
  #pragma unroll
  for (int pos = 0; pos < 27; pos++)
    sBuf[(wv * 27 + pos) * 64 + oc2] = acc2[pos];
  __syncthreads();
  float* sH = sBuf + kHOff;           // h[k], k = o*27 + pos
  for (int idx = t; idx < 1728; idx += 256) {
    int o = idx & 63, pos = idx >> 6;
    float v = sBuf[pos * 64 + o] + sBuf[(27 + pos) * 64 + o] +
              sBuf[(54 + pos) * 64 + o] + sBuf[(81 + pos) * 64 + o];
    sH[o * 27 + pos] = fmaxf(v + c2b[o], 0.f);
  }
  __syncthreads();

  // ---- fc1 (n = t) + fc2 + tanh (r16 form) ----
  float acc1 = 0.f;
  if (WPACK) {
    const float4* w4p = (const float4*)fw1;          // W1T4[k4][n]
    const float4* sH4 = (const float4*)sH;
    #pragma unroll 8
    for (int k4 = 0; k4 < 432; k4++) {
      float4 w  = w4p[k4 * 256 + t];
      float4 hv = sH4[k4];
      acc1 += w.x * hv.x + w.y * hv.y + w.z * hv.z + w.w * hv.w;
    }
  } else {
    const float* frow = fw1 + (size_t)t * 1728;
    #pragma unroll 8
    for (int k = 0; k < 1728; k++) acc1 += sH[k] * frow[k];
  }
  float h = fmaxf(acc1 + f1b[t], 0.f);
  sRed[t] = h * f2w[t];
  __syncthreads();
  for (int o = 128; o > 0; o >>= 1) {
    if (t < o) sRed[t] += sRed[t + o];
    __syncthreads();
  }
  float2 rk;
  rk.x = tanhf(sRed[0] + f2b[0]) * keep;
  rk.y = keep;
  __syncthreads();
  return rk;
}

// ---- pack f1w[n][k] -> W1T4[k4][n] ----
__global__ void dmr21_tr(const float* __restrict__ f1w, float* __restrict__ w1t4) {
  int k4 = blockIdx.x;                 // 0..431
  int n  = threadIdx.x;                // 0..255
  const float* s = f1w + (size_t)n * 1728 + k4 * 4;
  float4 w; w.x = s[0]; w.y = s[1]; w.z = s[2]; w.w = s[3];
  ((float4*)w1t4)[k4 * 256 + n] = w;
}

// ---- hot kernel (identifier-named): one patch per block ----
__global__ __launch_bounds__(256, 2)
void DMMRLoss_52621939310662_kernel(
    const float* __restrict__ src, const float* __restrict__ tgt,
    const float* __restrict__ c1w, const float* __restrict__ c1b,
    const float* __restrict__ c2w, const float* __restrict__ c2b,
    const float* __restrict__ w1t4, const float* __restrict__ f1b,
    const float* __restrict__ f2w, const float* __restrict__ f2b,
    float* __restrict__ pr, float* __restrict__ pk) {
  __shared__ float sBuf[8832];
  __shared__ float sRed[256];
  int t = threadIdx.x;
  float2 rk = dmr21_patch<true>(blockIdx.x, t, src, tgt, c1w, c1b, c2w, c2b,
                                w1t4, f1b, f2w, f2b, sBuf, sRed);
  if (t == 0) { pr[blockIdx.x] = rk.x; pk[blockIdx.x] = rk.y; }
}

// ---- raw hot fallback (ws too small for the pack) ----
__global__ __launch_bounds__(256, 2)
void dmr21_hot_raw(const float* __restrict__ src, const float* __restrict__ tgt,
                   const float* __restrict__ c1w, const float* __restrict__ c1b,
                   const float* __restrict__ c2w, const float* __restrict__ c2b,
                   const float* __restrict__ f1w, const float* __restrict__ f1b,
                   const float* __restrict__ f2w, const float* __restrict__ f2b,
                   float* __restrict__ pr, float* __restrict__ pk) {
  __shared__ float sBuf[8832];
  __shared__ float sRed[256];
  int t = threadIdx.x;
  float2 rk = dmr21_patch<false>(blockIdx.x, t, src, tgt, c1w, c1b, c2w, c2b,
                                 f1w, f1b, f2w, f2b, sBuf, sRed);
  if (t == 0) { pr[blockIdx.x] = rk.x; pk[blockIdx.x] = rk.y; }
}

// ---- final reduce -> float32 scalar ----
__global__ void dmr21_reduce(const float* __restrict__ pr, const float* __restrict__ pk,
                             float* __restrict__ out) {
  __shared__ float s1[256], s2[256];
  int t = threadIdx.x;
  float a = 0.f, b = 0.f;
  for (int p = t; p < 2197; p += 256) { a += pr[p]; b += pk[p]; }
  s1[t] = a; s2[t] = b;
  __syncthreads();
  for (int o = 128; o > 0; o >>= 1) {
    if (t < o) { s1[t] += s1[t + o]; s2[t] += s2[t + o]; }
    __syncthreads();
  }
  if (t == 0) out[0] = s1[0] / s2[0];
}

// ---- ws-free fallback: single block does everything ----
__global__ __launch_bounds__(256, 2)
void dmr21_solo(const float* __restrict__ src, const float* __restrict__ tgt,
                const float* __restrict__ c1w, const float* __restrict__ c1b,
                const float* __restrict__ c2w, const float* __restrict__ c2b,
                const float* __restrict__ f1w, const float* __restrict__ f1b,
                const float* __restrict__ f2w, const float* __restrict__ f2b,
                float* __restrict__ out) {
  __shared__ float sBuf[8832];
  __shared__ float sRed[256];
  __shared__ float sAcc[2];
  int t = threadIdx.x;
  if (t == 0) { sAcc[0] = 0.f; sAcc[1] = 0.f; }
  for (int p = 0; p < 2197; p++) {
    __syncthreads();
    float2 rk = dmr21_patch<false>(p, t, src, tgt, c1w, c1b, c2w, c2b,
                                   f1w, f1b, f2w, f2b, sBuf, sRed);
    if (t == 0) { sAcc[0] += rk.x; sAcc[1] += rk.y; }
  }
  __syncthreads();
  if (t == 0) out[0] = sAcc[0] / sAcc[1];
}

extern "C" void kernel_launch(void* const* d_in, const int* in_sizes, int n_in,
                              void* d_out, int out_size, void* d_ws, size_t ws_size,
                              hipStream_t stream) {
  const float* src = (const float*)d_in[0];   // source = moving
  const float* tgt = (const float*)d_in[1];   // target = fixed
  const float* c1w = (const float*)d_in[2];
  const float* c1b = (const float*)d_in[3];
  const float* c2w = (const float*)d_in[4];
  const float* c2b = (const float*)d_in[5];
  const float* f1w = (const float*)d_in[6];
  const float* f1b = (const float*)d_in[7];
  const float* f2w = (const float*)d_in[8];
  const float* f2b = (const float*)d_in[9];
  float* out = (float*)d_out;

  const size_t nW1T = 442368;                 // 1728*256
  const size_t nPK  = 2 * 2197;
  if (d_ws && ws_size >= (nW1T + nPK) * sizeof(float)) {
    float* w1t4 = (float*)d_ws;               // 16B-aligned at ws+0
    float* pr   = w1t4 + nW1T;
    float* pk   = pr + 2197;
    dmr21_tr<<<432, 256, 0, stream>>>(f1w, w1t4);
    DMMRLoss_52621939310662_kernel<<<2197, 256, 0, stream>>>(
        src, tgt, c1w, c1b, c2w, c2b, w1t4, f1b, f2w, f2b, pr, pk);
    dmr21_reduce<<<1, 256, 0, stream>>>(pr, pk, out);
  } else if (d_ws && ws_size >= nPK * sizeof(float)) {
    float* pr = (float*)d_ws;
    float* pk = pr + 2197;
    dmr21_hot_raw<<<2197, 256, 0, stream>>>(
        src, tgt, c1w, c1b, c2w, c2b, f1w, f1b, f2w, f2b, pr, pk);
    dmr21_reduce<<<1, 256, 0, stream>>>(pr, pk, out);
  } else {
    dmr21_solo<<<1, 256, 0, stream>>>(
        src, tgt, c1w, c1b, c2w, c2b, f1w, f1b, f2w, f2b, out);
  }
}

// Round 22
// 440.983 us; speedup vs baseline: 2.1089x; 2.1089x over previous
//
#include <hip/hip_runtime.h>

// DMMRLoss_52621939310662 — round 22: r16 conv (exact) + fc1 split into a
// register-blocked GEMM kernel.
// r21 lesson (3rd time): >~70 live floats in conv -> spill, any bounds hint.
// Conv phase here is byte-identical to r16 (438us champion). fc1 leaves the
// hot kernel: h written to global (k' = pos*64+o, coalesced), GEMM blocks
// 32 patches x 64 n with 8 outputs/thread -> 4x fewer wave-LDS reads than
// fused form; fc2 partials (4 n-groups) fold into the final reduce.

static constexpr int kPS = 433;    // staging plane stride (4-way floor)
static constexpr int kRS = 25;     // staging row stride
static constexpr int kCS = 528;    // conv1-out channel stride
static constexpr int kZS = 66;     // conv1-out z stride (y stride = 8)

// ---------------- hot kernel: conv1+conv2 per patch -> h2[p][k'], pk[p] ----
__global__ __launch_bounds__(256, 4)
void DMMRLoss_52621939310662_kernel(
    const float* __restrict__ src, const float* __restrict__ tgt,
    const float* __restrict__ c1w, const float* __restrict__ c1b,
    const float* __restrict__ c2w, const float* __restrict__ c2b,
    float* __restrict__ h2, float* __restrict__ pk) {
  __shared__ float sBuf[8704];
  __shared__ float sRed[256];
  int p = blockIdx.x;
  int t = threadIdx.x;
  int pd = p / 169; int rem = p - pd * 169; int phh = rem / 13; int pww = rem - phh * 13;
  int z0 = pd * 17, y0 = phh * 17, x0 = pww * 17;

  int wv  = t >> 6;
  int od  = (t >> 3) & 7, oh = t & 7;
  int oc2 = t & 63;

  // stage tgt + count zeros
  float cnt = 0.f;
  for (int idx = t; idx < 4913; idx += 256) {
    int a = idx / 289; int r2 = idx - a * 289; int b = r2 / 17; int c = r2 - b * 17;
    float v = tgt[((size_t)(z0 + a) * 222 + (y0 + b)) * 222 + (x0 + c)];
    sBuf[a * kPS + b * kRS + c] = v;
    if (v == 0.0f) cnt += 1.f;
  }
  sRed[t] = cnt;
  __syncthreads();
  for (int o = 128; o > 0; o >>= 1) {
    if (t < o) sRed[t] += sRed[t + o];
    __syncthreads();
  }
  float keep = (sRed[0] / 4913.0f <= 0.5f) ? 1.0f : 0.0f;
  if (t == 0) pk[p] = keep;
  __syncthreads();

  float acc2[27];
  #pragma unroll
  for (int i = 0; i < 27; i++) acc2[i] = 0.f;

  #pragma unroll 1
  for (int half = 0; half < 2; half++) {
    float acc[4][8];
    #pragma unroll
    for (int i = 0; i < 4; i++)
      #pragma unroll
      for (int j = 0; j < 8; j++) acc[i][j] = 0.f;

    #pragma unroll 1
    for (int ic = 0; ic < 2; ic++) {
      if (half + ic > 0) {
        const float* vol = ic ? src : tgt;
        __syncthreads();
        for (int idx = t; idx < 4913; idx += 256) {
          int a = idx / 289; int r2 = idx - a * 289; int b = r2 / 17; int c = r2 - b * 17;
          sBuf[a * kPS + b * kRS + c] =
              vol[((size_t)(z0 + a) * 222 + (y0 + b)) * 222 + (x0 + c)];
        }
        __syncthreads();
      }
      #pragma unroll 1
      for (int td = 0; td < 3; td++) {
        #pragma unroll 1
        for (int th = 0; th < 3; th++) {
          int rbase = (2 * od + td) * kPS + (2 * oh + th) * kRS;
          float a[17];
          #pragma unroll
          for (int x = 0; x < 17; x++) a[x] = sBuf[rbase + x];
          #pragma unroll
          for (int ocr = 0; ocr < 4; ocr++) {
            int oc = half * 16 + wv * 4 + ocr;
            const float* wp = c1w + oc * 54 + ic * 27 + td * 9 + th * 3;
            float w0 = wp[0], w1 = wp[1], w2 = wp[2];
            #pragma unroll
            for (int ow = 0; ow < 8; ow++)
              acc[ocr][ow] += a[2 * ow] * w0 + a[2 * ow + 1] * w1 + a[2 * ow + 2] * w2;
          }
        }
      }
    }
    __syncthreads();
    #pragma unroll
    for (int ocr = 0; ocr < 4; ocr++) {
      int lo = wv * 4 + ocr;
      float b = c1b[half * 16 + lo];
      int base = lo * kCS + od * kZS + oh * 8;
      #pragma unroll
      for (int ow = 0; ow < 8; ow++)
        sBuf[base + ow] = fmaxf(acc[ocr][ow] + b, 0.f);
    }
    __syncthreads();

    #pragma unroll 1
    for (int icr = 0; icr < 4; icr++) {
      int icl = wv * 4 + icr;
      int ic  = half * 16 + icl;
      const float* cbase = sBuf + icl * kCS;
      #pragma unroll 1
      for (int td = 0; td < 3; td++) {
        #pragma unroll 1
        for (int th = 0; th < 3; th++) {
          const float* wp = c2w + oc2 * 864 + ic * 27 + td * 9 + th * 3;
          float w0 = wp[0], w1 = wp[1], w2 = wp[2];
          #pragma unroll
          for (int zo = 0; zo < 3; zo++) {
            #pragma unroll
            for (int yo = 0; yo < 3; yo++) {
              const float* rp = cbase + (2 * zo + td) * kZS + (2 * yo + th) * 8;
              #pragma unroll
              for (int xo = 0; xo < 3; xo++)
                acc2[zo * 9 + yo * 3 + xo] +=
                    rp[2 * xo] * w0 + rp[2 * xo + 1] * w1 + rp[2 * xo + 2] * w2;
            }
          }
        }
      }
    }
  }
  __syncthreads();
  #pragma unroll
  for (int pos = 0; pos < 27; pos++)
    sBuf[(wv * 27 + pos) * 64 + oc2] = acc2[pos];
  __syncthreads();
  // reduce partials -> h2[p][k'] (k' = idx = pos*64+o), coalesced global write
  float* h2p = h2 + (size_t)p * 1728;
  for (int idx = t; idx < 1728; idx += 256) {
    int o = idx & 63, pos = idx >> 6;
    float v = sBuf[pos * 64 + o] + sBuf[(27 + pos) * 64 + o] +
              sBuf[(54 + pos) * 64 + o] + sBuf[(81 + pos) * 64 + o];
    h2p[idx] = fmaxf(v + c2b[o], 0.f);
  }
}

// ---- pack f1w[n][k] -> wp4[k4][n] float4 over k' = pos*64+o order ----
__global__ void dmr22_pack(const float* __restrict__ f1w, float* __restrict__ wp4) {
  int k4 = blockIdx.x;                 // 0..431
  int n  = threadIdx.x;                // 0..255
  float4 w;
  float* pw = (float*)&w;
  #pragma unroll
  for (int j = 0; j < 4; j++) {
    int kp = k4 * 4 + j;               // k' index
    int o = kp & 63, pos = kp >> 6;
    pw[j] = f1w[(size_t)n * 1728 + (o * 27 + pos)];
  }
  ((float4*)wp4)[(size_t)k4 * 256 + n] = w;
}

// ---- fc1 GEMM: 276 blocks = 69 pgroups x 4 ngroups; 8 patches/thread ----
static constexpr int kKT = 192;       // k-tile
static constexpr int kTS = 36;        // tile row stride (16B-aligned rows)

__global__ __launch_bounds__(256, 4)
void dmr22_gemm(const float* __restrict__ h2, const float* __restrict__ wp4,
                const float* __restrict__ f1b, const float* __restrict__ f2w,
                float* __restrict__ part) {
  __shared__ float sT[kKT * kTS];     // 27.6 KB
  int b = blockIdx.x;
  int pg = b >> 2, ng = b & 3;
  int p0 = pg * 32;
  int t = threadIdx.x;
  int n = ng * 64 + (t & 63);
  int pgrp = t >> 6;                  // wave id -> patch subgroup (8 patches)

  float acc[8];
  #pragma unroll
  for (int i = 0; i < 8; i++) acc[i] = 0.f;

  #pragma unroll 1
  for (int kt = 0; kt < 1728; kt += kKT) {
    __syncthreads();                  // previous tile reads done
    // stage h tile: [kk][pp], coalesced global reads
    #pragma unroll 1
    for (int i = 0; i < (32 * kKT) / 256; i++) {
      int idx = i * 256 + t;
      int pp = idx / kKT, kk = idx - pp * kKT;
      sT[kk * kTS + pp] = h2[(size_t)(p0 + pp) * 1728 + kt + kk];
    }
    __syncthreads();
    #pragma unroll 2
    for (int k4 = 0; k4 < kKT / 4; k4++) {
      float4 w = ((const float4*)wp4)[(size_t)((kt >> 2) + k4) * 256 + n];
      const float* r0 = sT + (k4 * 4 + 0) * kTS + pgrp * 8;
      const float* r1 = sT + (k4 * 4 + 1) * kTS + pgrp * 8;
      const float* r2 = sT + (k4 * 4 + 2) * kTS + pgrp * 8;
      const float* r3 = sT + (k4 * 4 + 3) * kTS + pgrp * 8;
      float4 a0 = *(const float4*)r0, b0 = *(const float4*)(r0 + 4);
      float4 a1 = *(const float4*)r1, b1 = *(const float4*)(r1 + 4);
      float4 a2 = *(const float4*)r2, b2 = *(const float4*)(r2 + 4);
      float4 a3 = *(const float4*)r3, b3 = *(const float4*)(r3 + 4);
      acc[0] += w.x * a0.x + w.y * a1.x + w.z * a2.x + w.w * a3.x;
      acc[1] += w.x * a0.y + w.y * a1.y + w.z * a2.y + w.w * a3.y;
      acc[2] += w.x * a0.z + w.y * a1.z + w.z * a2.z + w.w * a3.z;
      acc[3] += w.x * a0.w + w.y * a1.w + w.z * a2.w + w.w * a3.w;
      acc[4] += w.x * b0.x + w.y * b1.x + w.z * b2.x + w.w * b3.x;
      acc[5] += w.x * b0.y + w.y * b1.y + w.z * b2.y + w.w * b3.y;
      acc[6] += w.x * b0.z + w.y * b1.z + w.z * b2.z + w.w * b3.z;
      acc[7] += w.x * b0.w + w.y * b1.w + w.z * b2.w + w.w * b3.w;
    }
  }
  // epilogue: relu+bias, fc2 weight, reduce over 64 lanes (n within wave)
  float b1v = f1b[n], w2v = f2w[n];
  #pragma unroll
  for (int pp = 0; pp < 8; pp++) {
    float tl = fmaxf(acc[pp] + b1v, 0.f) * w2v;
    #pragma unroll
    for (int o = 32; o > 0; o >>= 1) tl += __shfl_down(tl, o, 64);
    if ((t & 63) == 0)
      part[(size_t)(p0 + pgrp * 8 + pp) * 4 + ng] = tl;
  }
}

// ---- final: fc2 bias + tanh + keep-masked mean -> float32 scalar ----
__global__ void dmr22_fin(const float* __restrict__ part, const float* __restrict__ pk,
                          const float* __restrict__ f2b, float* __restrict__ out) {
  __shared__ float s1[256], s2[256];
  int t = threadIdx.x;
  float b0 = f2b[0];
  float a = 0.f, b = 0.f;
  for (int p = t; p < 2197; p += 256) {
    float s = part[4 * p] + part[4 * p + 1] + part[4 * p + 2] + part[4 * p + 3];
    float kv = pk[p];
    a += tanhf(s + b0) * kv;
    b += kv;
  }
  s1[t] = a; s2[t] = b;
  __syncthreads();
  for (int o = 128; o > 0; o >>= 1) {
    if (t < o) { s1[t] += s1[t + o]; s2[t] += s2[t + o]; }
    __syncthreads();
  }
  if (t == 0) out[0] = s1[0] / s2[0];
}

// ---- ws-free fallback: single block, fully fused (r16 logic, slow) ----
__global__ __launch_bounds__(256, 2)
void dmr22_solo(const float* __restrict__ src, const float* __restrict__ tgt,
                const float* __restrict__ c1w, const float* __restrict__ c1b,
                const float* __restrict__ c2w, const float* __restrict__ c2b,
                const float* __restrict__ f1w, const float* __restrict__ f1b,
                const float* __restrict__ f2w, const float* __restrict__ f2b,
                float* __restrict__ out) {
  __shared__ float sBuf[8704];
  __shared__ float sH[1728];
  __shared__ float sRed[256];
  __shared__ float sAcc[2];
  int t = threadIdx.x;
  int wv = t >> 6, od = (t >> 3) & 7, oh = t & 7, oc2 = t & 63;
  if (t == 0) { sAcc[0] = 0.f; sAcc[1] = 0.f; }
  for (int p = 0; p < 2197; p++) {
    __syncthreads();
    int pd = p / 169; int rem = p - pd * 169; int phh = rem / 13; int pww = rem - phh * 13;
    int z0 = pd * 17, y0 = phh * 17, x0 = pww * 17;
    float cnt = 0.f;
    for (int idx = t; idx < 4913; idx += 256) {
      int a = idx / 289; int r2 = idx - a * 289; int b = r2 / 17; int c = r2 - b * 17;
      float v = tgt[((size_t)(z0 + a) * 222 + (y0 + b)) * 222 + (x0 + c)];
      sBuf[a * kPS + b * kRS + c] = v;
      if (v == 0.0f) cnt += 1.f;
    }
    sRed[t] = cnt;
    __syncthreads();
    for (int o = 128; o > 0; o >>= 1) {
      if (t < o) sRed[t] += sRed[t + o];
      __syncthreads();
    }
    float keep = (sRed[0] / 4913.0f <= 0.5f) ? 1.0f : 0.0f;
    __syncthreads();
    float acc2[27];
    for (int i = 0; i < 27; i++) acc2[i] = 0.f;
    #pragma unroll 1
    for (int half = 0; half < 2; half++) {
      float acc[4][8];
      for (int i = 0; i < 4; i++)
        for (int j = 0; j < 8; j++) acc[i][j] = 0.f;
      #pragma unroll 1
      for (int ic = 0; ic < 2; ic++) {
        if (half + ic > 0) {
          const float* vol = ic ? src : tgt;
          __syncthreads();
          for (int idx = t; idx < 4913; idx += 256) {
            int a = idx / 289; int r2 = idx - a * 289; int b = r2 / 17; int c = r2 - b * 17;
            sBuf[a * kPS + b * kRS + c] =
                vol[((size_t)(z0 + a) * 222 + (y0 + b)) * 222 + (x0 + c)];
          }
          __syncthreads();
        }
        #pragma unroll 1
        for (int td = 0; td < 3; td++) {
          #pragma unroll 1
          for (int th = 0; th < 3; th++) {
            int rbase = (2 * od + td) * kPS + (2 * oh + th) * kRS;
            float a[17];
            #pragma unroll
            for (int x = 0; x < 17; x++) a[x] = sBuf[rbase + x];
            #pragma unroll
            for (int ocr = 0; ocr < 4; ocr++) {
              int oc = half * 16 + wv * 4 + ocr;
              const float* wp = c1w + oc * 54 + ic * 27 + td * 9 + th * 3;
              float w0 = wp[0], w1 = wp[1], w2 = wp[2];
              #pragma unroll
              for (int ow = 0; ow < 8; ow++)
                acc[ocr][ow] += a[2 * ow] * w0 + a[2 * ow + 1] * w1 + a[2 * ow + 2] * w2;
            }
          }
        }
      }
      __syncthreads();
      #pragma unroll
      for (int ocr = 0; ocr < 4; ocr++) {
        int lo = wv * 4 + ocr;
        float b = c1b[half * 16 + lo];
        int base = lo * kCS + od * kZS + oh * 8;
        #pragma unroll
        for (int ow = 0; ow < 8; ow++)
          sBuf[base + ow] = fmaxf(acc[ocr][ow] + b, 0.f);
      }
      __syncthreads();
      #pragma unroll 1
      for (int icr = 0; icr < 4; icr++) {
        int icl = wv * 4 + icr;
        int ic  = half * 16 + icl;
        const float* cbase = sBuf + icl * kCS;
        #pragma unroll 1
        for (int td = 0; td < 3; td++) {
          #pragma unroll 1
          for (int th = 0; th < 3; th++) {
            const float* wp = c2w + oc2 * 864 + ic * 27 + td * 9 + th * 3;
            float w0 = wp[0], w1 = wp[1], w2 = wp[2];
            #pragma unroll
            for (int zo = 0; zo < 3; zo++) {
              #pragma unroll
              for (int yo = 0; yo < 3; yo++) {
                const float* rp = cbase + (2 * zo + td) * kZS + (2 * yo + th) * 8;
                #pragma unroll
                for (int xo = 0; xo < 3; xo++)
                  acc2[zo * 9 + yo * 3 + xo] +=
                      rp[2 * xo] * w0 + rp[2 * xo + 1] * w1 + rp[2 * xo + 2] * w2;
              }
            }
          }
        }
      }
    }
    __syncthreads();
    #pragma unroll
    for (int pos = 0; pos < 27; pos++)
      sBuf[(wv * 27 + pos) * 64 + oc2] = acc2[pos];
    __syncthreads();
    for (int idx = t; idx < 1728; idx += 256) {
      int o = idx & 63, pos = idx >> 6;
      float v = sBuf[pos * 64 + o] + sBuf[(27 + pos) * 64 + o] +
                sBuf[(54 + pos) * 64 + o] + sBuf[(81 + pos) * 64 + o];
      sH[o * 27 + pos] = fmaxf(v + c2b[o], 0.f);
    }
    __syncthreads();
    float acc1 = 0.f;
    const float* frow = f1w + (size_t)t * 1728;
    #pragma unroll 8
    for (int k = 0; k < 1728; k++) acc1 += sH[k] * frow[k];
    float h = fmaxf(acc1 + f1b[t], 0.f);
    sRed[t] = h * f2w[t];
    __syncthreads();
    for (int o = 128; o > 0; o >>= 1) {
      if (t < o) sRed[t] += sRed[t + o];
      __syncthreads();
    }
    if (t == 0) {
      sAcc[0] += tanhf(sRed[0] + f2b[0]) * keep;
      sAcc[1] += keep;
    }
  }
  __syncthreads();
  if (t == 0) out[0] = sAcc[0] / sAcc[1];
}

extern "C" void kernel_launch(void* const* d_in, const int* in_sizes, int n_in,
                              void* d_out, int out_size, void* d_ws, size_t ws_size,
                              hipStream_t stream) {
  const float* src = (const float*)d_in[0];   // source = moving
  const float* tgt = (const float*)d_in[1];   // target = fixed
  const float* c1w = (const float*)d_in[2];
  const float* c1b = (const float*)d_in[3];
  const float* c2w = (const float*)d_in[4];
  const float* c2b = (const float*)d_in[5];
  const float* f1w = (const float*)d_in[6];
  const float* f1b = (const float*)d_in[7];
  const float* f2w = (const float*)d_in[8];
  const float* f2b = (const float*)d_in[9];
  float* out = (float*)d_out;

  const size_t nWP  = 442368;        // wp4: 1728*256
  const size_t nH2  = (size_t)2208 * 1728;
  const size_t nPart = 2208 * 4;
  const size_t nPk  = 2208;
  if (d_ws && ws_size >= (nWP + nH2 + nPart + nPk) * sizeof(float)) {
    float* wp4  = (float*)d_ws;      // 16B-aligned
    float* h2   = wp4 + nWP;
    float* part = h2 + nH2;
    float* pk   = part + nPart;
    dmr22_pack<<<432, 256, 0, stream>>>(f1w, wp4);
    DMMRLoss_52621939310662_kernel<<<2197, 256, 0, stream>>>(
        src, tgt, c1w, c1b, c2w, c2b, h2, pk);
    dmr22_gemm<<<276, 256, 0, stream>>>(h2, wp4, f1b, f2w, part);
    dmr22_fin<<<1, 256, 0, stream>>>(part, pk, f2b, out);
  } else {
    dmr22_solo<<<1, 256, 0, stream>>>(
        src, tgt, c1w, c1b, c2w, c2b, f1w, f1b, f2w, f2b, out);
  }
}

// Round 23
// 420.194 us; speedup vs baseline: 2.2133x; 1.0495x over previous
//
#include <hip/hip_runtime.h>

// DMMRLoss_52621939310662 — round 23: r22 hot conv (exact, proven spill-free)
// + GEMM v2 (4n x 2p per thread, 6 reads/32 FMA vs 9/32) + shfl keep-reduce.
// wp4 format: [k'][n4] float4 over n (4 consecutive n per read).
// h2 tile staged [pp][kk] stride 196 (16B-aligned rows).

static constexpr int kPS = 433;    // staging plane stride (4-way floor)
static constexpr int kRS = 25;     // staging row stride
static constexpr int kCS = 528;    // conv1-out channel stride
static constexpr int kZS = 66;     // conv1-out z stride (y stride = 8)

// ---------------- hot kernel: conv1+conv2 per patch -> h2[p][k'], pk[p] ----
__global__ __launch_bounds__(256, 4)
void DMMRLoss_52621939310662_kernel(
    const float* __restrict__ src, const float* __restrict__ tgt,
    const float* __restrict__ c1w, const float* __restrict__ c1b,
    const float* __restrict__ c2w, const float* __restrict__ c2b,
    float* __restrict__ h2, float* __restrict__ pk) {
  __shared__ float sBuf[8704];
  __shared__ float sRed[4];
  int p = blockIdx.x;
  int t = threadIdx.x;
  int pd = p / 169; int rem = p - pd * 169; int phh = rem / 13; int pww = rem - phh * 13;
  int z0 = pd * 17, y0 = phh * 17, x0 = pww * 17;

  int wv  = t >> 6;
  int od  = (t >> 3) & 7, oh = t & 7;
  int oc2 = t & 63;

  // stage tgt + count zeros (shfl reduce, one barrier)
  float cnt = 0.f;
  for (int idx = t; idx < 4913; idx += 256) {
    int a = idx / 289; int r2 = idx - a * 289; int b = r2 / 17; int c = r2 - b * 17;
    float v = tgt[((size_t)(z0 + a) * 222 + (y0 + b)) * 222 + (x0 + c)];
    sBuf[a * kPS + b * kRS + c] = v;
    if (v == 0.0f) cnt += 1.f;
  }
  #pragma unroll
  for (int o = 32; o > 0; o >>= 1) cnt += __shfl_down(cnt, o, 64);
  if ((t & 63) == 0) sRed[wv] = cnt;
  __syncthreads();                    // staged tgt + counts visible
  float keep = ((sRed[0] + sRed[1] + sRed[2] + sRed[3]) / 4913.0f <= 0.5f) ? 1.0f : 0.0f;
  if (t == 0) pk[p] = keep;

  float acc2[27];
  #pragma unroll
  for (int i = 0; i < 27; i++) acc2[i] = 0.f;

  #pragma unroll 1
  for (int half = 0; half < 2; half++) {
    float acc[4][8];
    #pragma unroll
    for (int i = 0; i < 4; i++)
      #pragma unroll
      for (int j = 0; j < 8; j++) acc[i][j] = 0.f;

    #pragma unroll 1
    for (int ic = 0; ic < 2; ic++) {
      if (half + ic > 0) {
        const float* vol = ic ? src : tgt;
        __syncthreads();
        for (int idx = t; idx < 4913; idx += 256) {
          int a = idx / 289; int r2 = idx - a * 289; int b = r2 / 17; int c = r2 - b * 17;
          sBuf[a * kPS + b * kRS + c] =
              vol[((size_t)(z0 + a) * 222 + (y0 + b)) * 222 + (x0 + c)];
        }
        __syncthreads();
      }
      #pragma unroll 1
      for (int td = 0; td < 3; td++) {
        #pragma unroll 1
        for (int th = 0; th < 3; th++) {
          int rbase = (2 * od + td) * kPS + (2 * oh + th) * kRS;
          float a[17];
          #pragma unroll
          for (int x = 0; x < 17; x++) a[x] = sBuf[rbase + x];
          #pragma unroll
          for (int ocr = 0; ocr < 4; ocr++) {
            int oc = half * 16 + wv * 4 + ocr;
            const float* wp = c1w + oc * 54 + ic * 27 + td * 9 + th * 3;
            float w0 = wp[0], w1 = wp[1], w2 = wp[2];
            #pragma unroll
            for (int ow = 0; ow < 8; ow++)
              acc[ocr][ow] += a[2 * ow] * w0 + a[2 * ow + 1] * w1 + a[2 * ow + 2] * w2;
          }
        }
      }
    }
    __syncthreads();
    #pragma unroll
    for (int ocr = 0; ocr < 4; ocr++) {
      int lo = wv * 4 + ocr;
      float b = c1b[half * 16 + lo];
      int base = lo * kCS + od * kZS + oh * 8;
      #pragma unroll
      for (int ow = 0; ow < 8; ow++)
        sBuf[base + ow] = fmaxf(acc[ocr][ow] + b, 0.f);
    }
    __syncthreads();

    #pragma unroll 1
    for (int icr = 0; icr < 4; icr++) {
      int icl = wv * 4 + icr;
      int ic  = half * 16 + icl;
      const float* cbase = sBuf + icl * kCS;
      #pragma unroll 1
      for (int td = 0; td < 3; td++) {
        #pragma unroll 1
        for (int th = 0; th < 3; th++) {
          const float* wp = c2w + oc2 * 864 + ic * 27 + td * 9 + th * 3;
          float w0 = wp[0], w1 = wp[1], w2 = wp[2];
          #pragma unroll
          for (int zo = 0; zo < 3; zo++) {
            #pragma unroll
            for (int yo = 0; yo < 3; yo++) {
              const float* rp = cbase + (2 * zo + td) * kZS + (2 * yo + th) * 8;
              #pragma unroll
              for (int xo = 0; xo < 3; xo++)
                acc2[zo * 9 + yo * 3 + xo] +=
                    rp[2 * xo] * w0 + rp[2 * xo + 1] * w1 + rp[2 * xo + 2] * w2;
            }
          }
        }
      }
    }
  }
  __syncthreads();
  #pragma unroll
  for (int pos = 0; pos < 27; pos++)
    sBuf[(wv * 27 + pos) * 64 + oc2] = acc2[pos];
  __syncthreads();
  float* h2p = h2 + (size_t)p * 1728;
  for (int idx = t; idx < 1728; idx += 256) {
    int o = idx & 63, pos = idx >> 6;
    float v = sBuf[pos * 64 + o] + sBuf[(27 + pos) * 64 + o] +
              sBuf[(54 + pos) * 64 + o] + sBuf[(81 + pos) * 64 + o];
    h2p[idx] = fmaxf(v + c2b[o], 0.f);       // k' = pos*64+o, coalesced
  }
}

// ---- pack f1w[n][k] -> wp4[k'][n4] float4 over n (k' = pos*64+o order) ----
__global__ void dmr23_pack(const float* __restrict__ f1w, float* __restrict__ wp4) {
  int gid = blockIdx.x * 256 + threadIdx.x;  // 432 blocks -> 1728*64
  int kp = gid >> 6, n4 = gid & 63;
  int o = kp & 63, pos = kp >> 6;
  int korig = o * 27 + pos;
  float4 w;
  w.x = f1w[(size_t)(n4 * 4 + 0) * 1728 + korig];
  w.y = f1w[(size_t)(n4 * 4 + 1) * 1728 + korig];
  w.z = f1w[(size_t)(n4 * 4 + 2) * 1728 + korig];
  w.w = f1w[(size_t)(n4 * 4 + 3) * 1728 + korig];
  ((float4*)wp4)[gid] = w;
}

// ---- fc1 GEMM v2: 276 blocks = 69 pg x 4 ng; 32p x 64n; 4n x 2p/thread ----
static constexpr int kKT = 192;       // k-tile
static constexpr int kTS = 196;       // tile row stride (floats, mult of 4)

__global__ __launch_bounds__(256, 4)
void dmr23_gemm(const float* __restrict__ h2, const float* __restrict__ wp4,
                const float* __restrict__ f1b, const float* __restrict__ f2w,
                float* __restrict__ part) {
  __shared__ float sT[32 * kTS];      // 25.1 KB: [pp][kk]
  int b = blockIdx.x;
  int pg = b >> 2, ng = b & 3;
  int p0 = pg * 32;
  int t = threadIdx.x;
  int n4l = t & 15;                   // 16 n-quads -> 64 n
  int n4 = ng * 16 + n4l;             // global n-quad
  int pgrp = t >> 4;                  // 0..15, 2 patches each
  int pA = pgrp * 2, pB = pA + 1;

  float acc[4][2];
  #pragma unroll
  for (int j = 0; j < 4; j++) { acc[j][0] = 0.f; acc[j][1] = 0.f; }

  #pragma unroll 1
  for (int kt = 0; kt < 1728; kt += kKT) {
    __syncthreads();                  // previous tile reads done
    // stage: 32p x 192k = 1536 float4, 6 per thread, coalesced along k
    #pragma unroll
    for (int i = 0; i < 6; i++) {
      int idx = i * 256 + t;
      int pp = idx / 48, kq = idx - pp * 48;
      float4 v = *(const float4*)(h2 + (size_t)(p0 + pp) * 1728 + kt + kq * 4);
      *(float4*)(sT + pp * kTS + kq * 4) = v;
    }
    __syncthreads();
    #pragma unroll 2
    for (int k4 = 0; k4 < kKT / 4; k4++) {
      int kb = kt + k4 * 4;
      float4 w0 = ((const float4*)wp4)[(size_t)(kb + 0) * 64 + n4];
      float4 w1 = ((const float4*)wp4)[(size_t)(kb + 1) * 64 + n4];
      float4 w2 = ((const float4*)wp4)[(size_t)(kb + 2) * 64 + n4];
      float4 w3 = ((const float4*)wp4)[(size_t)(kb + 3) * 64 + n4];
      float4 hA = *(const float4*)(sT + pA * kTS + k4 * 4);
      float4 hB = *(const float4*)(sT + pB * kTS + k4 * 4);
      acc[0][0] += w0.x * hA.x + w1.x * hA.y + w2.x * hA.z + w3.x * hA.w;
      acc[1][0] += w0.y * hA.x + w1.y * hA.y + w2.y * hA.z + w3.y * hA.w;
      acc[2][0] += w0.z * hA.x + w1.z * hA.y + w2.z * hA.z + w3.z * hA.w;
      acc[3][0] += w0.w * hA.x + w1.w * hA.y + w2.w * hA.z + w3.w * hA.w;
      acc[0][1] += w0.x * hB.x + w1.x * hB.y + w2.x * hB.z + w3.x * hB.w;
      acc[1][1] += w0.y * hB.x + w1.y * hB.y + w2.y * hB.z + w3.y * hB.w;
      acc[2][1] += w0.z * hB.x + w1.z * hB.y + w2.z * hB.z + w3.z * hB.w;
      acc[3][1] += w0.w * hB.x + w1.w * hB.y + w2.w * hB.z + w3.w * hB.w;
    }
  }
  // epilogue: bias+relu, fc2 weight, reduce over the 16 n4-lanes
  float b0 = f1b[n4 * 4 + 0], b1 = f1b[n4 * 4 + 1];
  float b2 = f1b[n4 * 4 + 2], b3 = f1b[n4 * 4 + 3];
  float v0 = f2w[n4 * 4 + 0], v1 = f2w[n4 * 4 + 1];
  float v2 = f2w[n4 * 4 + 2], v3 = f2w[n4 * 4 + 3];
  #pragma unroll
  for (int pp = 0; pp < 2; pp++) {
    float tl = fmaxf(acc[0][pp] + b0, 0.f) * v0 + fmaxf(acc[1][pp] + b1, 0.f) * v1 +
               fmaxf(acc[2][pp] + b2, 0.f) * v2 + fmaxf(acc[3][pp] + b3, 0.f) * v3;
    #pragma unroll
    for (int o = 8; o > 0; o >>= 1) tl += __shfl_down(tl, o, 16);
    if (n4l == 0)
      part[(size_t)(p0 + pA + pp) * 4 + ng] = tl;
  }
}

// ---- final: fc2 bias + tanh + keep-masked mean -> float32 scalar ----
__global__ void dmr23_fin(const float* __restrict__ part, const float* __restrict__ pk,
                          const float* __restrict__ f2b, float* __restrict__ out) {
  __shared__ float s1[256], s2[256];
  int t = threadIdx.x;
  float b0 = f2b[0];
  float a = 0.f, b = 0.f;
  for (int p = t; p < 2197; p += 256) {
    float s = part[4 * p] + part[4 * p + 1] + part[4 * p + 2] + part[4 * p + 3];
    float kv = pk[p];
    a += tanhf(s + b0) * kv;
    b += kv;
  }
  s1[t] = a; s2[t] = b;
  __syncthreads();
  for (int o = 128; o > 0; o >>= 1) {
    if (t < o) { s1[t] += s1[t + o]; s2[t] += s2[t + o]; }
    __syncthreads();
  }
  if (t == 0) out[0] = s1[0] / s2[0];
}

// ---- ws-free fallback: single block, fully fused (r16 logic, slow) ----
__global__ __launch_bounds__(256, 2)
void dmr23_solo(const float* __restrict__ src, const float* __restrict__ tgt,
                const float* __restrict__ c1w, const float* __restrict__ c1b,
                const float* __restrict__ c2w, const float* __restrict__ c2b,
                const float* __restrict__ f1w, const float* __restrict__ f1b,
                const float* __restrict__ f2w, const float* __restrict__ f2b,
                float* __restrict__ out) {
  __shared__ float sBuf[8704];
  __shared__ float sH[1728];
  __shared__ float sRed[256];
  __shared__ float sAcc[2];
  int t = threadIdx.x;
  int wv = t >> 6, od = (t >> 3) & 7, oh = t & 7, oc2 = t & 63;
  if (t == 0) { sAcc[0] = 0.f; sAcc[1] = 0.f; }
  for (int p = 0; p < 2197; p++) {
    __syncthreads();
    int pd = p / 169; int rem = p - pd * 169; int phh = rem / 13; int pww = rem - phh * 13;
    int z0 = pd * 17, y0 = phh * 17, x0 = pww * 17;
    float cnt = 0.f;
    for (int idx = t; idx < 4913; idx += 256) {
      int a = idx / 289; int r2 = idx - a * 289; int b = r2 / 17; int c = r2 - b * 17;
      float v = tgt[((size_t)(z0 + a) * 222 + (y0 + b)) * 222 + (x0 + c)];
      sBuf[a * kPS + b * kRS + c] = v;
      if (v == 0.0f) cnt += 1.f;
    }
    sRed[t] = cnt;
    __syncthreads();
    for (int o = 128; o > 0; o >>= 1) {
      if (t < o) sRed[t] += sRed[t + o];
      __syncthreads();
    }
    float keep = (sRed[0] / 4913.0f <= 0.5f) ? 1.0f : 0.0f;
    __syncthreads();
    float acc2[27];
    for (int i = 0; i < 27; i++) acc2[i] = 0.f;
    #pragma unroll 1
    for (int half = 0; half < 2; half++) {
      float acc[4][8];
      for (int i = 0; i < 4; i++)
        for (int j = 0; j < 8; j++) acc[i][j] = 0.f;
      #pragma unroll 1
      for (int ic = 0; ic < 2; ic++) {
        if (half + ic > 0) {
          const float* vol = ic ? src : tgt;
          __syncthreads();
          for (int idx = t; idx < 4913; idx += 256) {
            int a = idx / 289; int r2 = idx - a * 289; int b = r2 / 17; int c = r2 - b * 17;
            sBuf[a * kPS + b * kRS + c] =
                vol[((size_t)(z0 + a) * 222 + (y0 + b)) * 222 + (x0 + c)];
          }
          __syncthreads();
        }
        #pragma unroll 1
        for (int td = 0; td < 3; td++) {
          #pragma unroll 1
          for (int th = 0; th < 3; th++) {
            int rbase = (2 * od + td) * kPS + (2 * oh + th) * kRS;
            float a[17];
            #pragma unroll
            for (int x = 0; x < 17; x++) a[x] = sBuf[rbase + x];
            #pragma unroll
            for (int ocr = 0; ocr < 4; ocr++) {
              int oc = half * 16 + wv * 4 + ocr;
              const float* wp = c1w + oc * 54 + ic * 27 + td * 9 + th * 3;
              float w0 = wp[0], w1 = wp[1], w2 = wp[2];
              #pragma unroll
              for (int ow = 0; ow < 8; ow++)
                acc[ocr][ow] += a[2 * ow] * w0 + a[2 * ow + 1] * w1 + a[2 * ow + 2] * w2;
            }
          }
        }
      }
      __syncthreads();
      #pragma unroll
      for (int ocr = 0; ocr < 4; ocr++) {
        int lo = wv * 4 + ocr;
        float b = c1b[half * 16 + lo];
        int base = lo * kCS + od * kZS + oh * 8;
        #pragma unroll
        for (int ow = 0; ow < 8; ow++)
          sBuf[base + ow] = fmaxf(acc[ocr][ow] + b, 0.f);
      }
      __syncthreads();
      #pragma unroll 1
      for (int icr = 0; icr < 4; icr++) {
        int icl = wv * 4 + icr;
        int ic  = half * 16 + icl;
        const float* cbase = sBuf + icl * kCS;
        #pragma unroll 1
        for (int td = 0; td < 3; td++) {
          #pragma unroll 1
          for (int th = 0; th < 3; th++) {
            const float* wp = c2w + oc2 * 864 + ic * 27 + td * 9 + th * 3;
            float w0 = wp[0], w1 = wp[1], w2 = wp[2];
            #pragma unroll
            for (int zo = 0; zo < 3; zo++) {
              #pragma unroll
              for (int yo = 0; yo < 3; yo++) {
                const float* rp = cbase + (2 * zo + td) * kZS + (2 * yo + th) * 8;
                #pragma unroll
                for (int xo = 0; xo < 3; xo++)
                  acc2[zo * 9 + yo * 3 + xo] +=
                      rp[2 * xo] * w0 + rp[2 * xo + 1] * w1 + rp[2 * xo + 2] * w2;
              }
            }
          }
        }
      }
    }
    __syncthreads();
    #pragma unroll
    for (int pos = 0; pos < 27; pos++)
      sBuf[(wv * 27 + pos) * 64 + oc2] = acc2[pos];
    __syncthreads();
    for (int idx = t; idx < 1728; idx += 256) {
      int o = idx & 63, pos = idx >> 6;
      float v = sBuf[pos * 64 + o] + sBuf[(27 + pos) * 64 + o] +
                sBuf[(54 + pos) * 64 + o] + sBuf[(81 + pos) * 64 + o];
      sH[o * 27 + pos] = fmaxf(v + c2b[o], 0.f);
    }
    __syncthreads();
    float acc1 = 0.f;
    const float* frow = f1w + (size_t)t * 1728;
    #pragma unroll 8
    for (int k = 0; k < 1728; k++) acc1 += sH[k] * frow[k];
    float h = fmaxf(acc1 + f1b[t], 0.f);
    sRed[t] = h * f2w[t];
    __syncthreads();
    for (int o = 128; o > 0; o >>= 1) {
      if (t < o) sRed[t] += sRed[t + o];
      __syncthreads();
    }
    if (t == 0) {
      sAcc[0] += tanhf(sRed[0] + f2b[0]) * keep;
      sAcc[1] += keep;
    }
  }
  __syncthreads();
  if (t == 0) out[0] = sAcc[0] / sAcc[1];
}

extern "C" void kernel_launch(void* const* d_in, const int* in_sizes, int n_in,
                              void* d_out, int out_size, void* d_ws, size_t ws_size,
                              hipStream_t stream) {
  const float* src = (const float*)d_in[0];   // source = moving
  const float* tgt = (const float*)d_in[1];   // target = fixed
  const float* c1w = (const float*)d_in[2];
  const float* c1b = (const float*)d_in[3];
  const float* c2w = (const float*)d_in[4];
  const float* c2b = (const float*)d_in[5];
  const float* f1w = (const float*)d_in[6];
  const float* f1b = (const float*)d_in[7];
  const float* f2w = (const float*)d_in[8];
  const float* f2b = (const float*)d_in[9];
  float* out = (float*)d_out;

  const size_t nWP   = 442368;       // wp4: 1728*64 float4
  const size_t nH2   = (size_t)2208 * 1728;
  const size_t nPart = 2208 * 4;
  const size_t nPk   = 2208;
  if (d_ws && ws_size >= (nWP + nH2 + nPart + nPk) * sizeof(float)) {
    float* wp4  = (float*)d_ws;      // 16B-aligned
    float* h2   = wp4 + nWP;
    float* part = h2 + nH2;
    float* pk   = part + nPart;
    dmr23_pack<<<432, 256, 0, stream>>>(f1w, wp4);
    DMMRLoss_52621939310662_kernel<<<2197, 256, 0, stream>>>(
        src, tgt, c1w, c1b, c2w, c2b, h2, pk);
    dmr23_gemm<<<276, 256, 0, stream>>>(h2, wp4, f1b, f2w, part);
    dmr23_fin<<<1, 256, 0, stream>>>(part, pk, f2b, out);
  } else {
    dmr23_solo<<<1, 256, 0, stream>>>(
        src, tgt, c1w, c1b, c2w, c2b, f1w, f1b, f2w, f2b, out);
  }
}